// Round 4
// baseline (535.526 us; speedup 1.0000x reference)
//
#include <hip/hip_runtime.h>
#include <hip/hip_fp16.h>

#define Bb   2
#define Cc   256
#define Nn   100000
#define Hh   256
#define Ww   256
#define HWp  65536
#define TOK  64
#define NBLK ((Nn + TOK - 1) / TOK)   // 1563
#define BUCK 24                        // bucket capacity per cell (Poisson-safe)

// ---------------- Kernel 1: LayerNorm(channel) -> ln_out (f16) + bucket fill ----------------
__global__ __launch_bounds__(256) void ln_bucket_kernel(
    const float* __restrict__ tokens, const int* __restrict__ fidx,
    const float* __restrict__ lnw, const float* __restrict__ lnb,
    __half* __restrict__ ln_out, int* __restrict__ cntInt, int* __restrict__ bucket)
{
    __shared__ __half2 xs[128][TOK + 1];   // [channel-pair][token]
    __shared__ float  ps[4][TOK];
    __shared__ float  pss[4][TOK];
    __shared__ float2 ms_s[TOK];           // (mu, rsqrt)

    const int tid = threadIdx.x;
    const int bt  = blockIdx.x;
    const int b   = bt / NBLK;
    const int n0  = (bt % NBLK) * TOK;
    const int tn  = tid & 63;
    const int q   = tid >> 6;
    const int nvalid = min(TOK, Nn - n0);

    // Phase A: load tokens tile [C][TOK] coalesced along n; accumulate stats inline.
    const float* tb = tokens + (size_t)b * Cc * Nn;
    __half* xsh = (__half*)&xs[0][0];
    float s = 0.f, ss = 0.f;
    #pragma unroll 8
    for (int i = 0; i < 64; ++i) {
        int c = i * 4 + q;
        float v = (tn < nvalid) ? tb[c * Nn + n0 + tn] : 0.0f;
        s += v; ss += v * v;
        xsh[(c >> 1) * (2 * (TOK + 1)) + 2 * tn + (c & 1)] = __float2half(v);
    }
    ps[q][tn] = s; pss[q][tn] = ss;

    // Bucket fill: one int atomic per token (cheap), no value atomics anywhere.
    if (tid < nvalid) {
        int bin  = fidx[b * Nn + n0 + tid];
        int cell = b * HWp + bin;
        int slot = atomicAdd(&cntInt[cell], 1);
        if (slot < BUCK) bucket[(size_t)cell * BUCK + slot] = n0 + tid;
    }
    __syncthreads();

    if (tid < TOK) {
        float sum = ps[0][tid] + ps[1][tid] + ps[2][tid] + ps[3][tid];
        float ssq = pss[0][tid] + pss[1][tid] + pss[2][tid] + pss[3][tid];
        float mu  = sum * (1.0f / Cc);
        float var = ssq * (1.0f / Cc) - mu * mu;
        ms_s[tid] = make_float2(mu, rsqrtf(var + 1e-5f));
    }
    __syncthreads();

    // Phase C: normalize + coalesced f16 write (token-major). 2 tokens / 256 thr -> 1KB chunks.
    const int cp  = tid & 127;
    const int hlf = tid >> 7;
    const float2 wv = *(const float2*)&lnw[2 * cp];
    const float2 bv = *(const float2*)&lnb[2 * cp];
    unsigned* lo = (unsigned*)ln_out;
    for (int t = hlf; t < nvalid; t += 2) {
        float2 mr = ms_s[t];
        float2 xf = __half22float2(xs[cp][t]);
        float x0 = (xf.x - mr.x) * mr.y * wv.x + bv.x;
        float x1 = (xf.y - mr.x) * mr.y * wv.y + bv.y;
        __half2 pk = __floats2half2_rn(x0, x1);
        lo[((size_t)b * Nn + n0 + t) * (Cc / 2) + cp] = *(unsigned*)&pk;
    }
}

// ---------------- Kernel 2: per-cell mean (wave per cell), writes ALL cells ----------------
__global__ __launch_bounds__(256) void cell_mean_kernel(
    const __half* __restrict__ ln_out, const int* __restrict__ cntInt,
    const int* __restrict__ bucket, __half* __restrict__ grid)
{
    const int wave = (int)((blockIdx.x * 256 + threadIdx.x) >> 6);  // = cell index (b*HW+hw)
    const int lane = threadIdx.x & 63;
    const int b    = wave >> 16;

    int cnt = min(cntInt[wave], BUCK);
    float a0 = 0.f, a1 = 0.f, a2 = 0.f, a3 = 0.f;
    for (int t = 0; t < cnt; ++t) {
        int tok = bucket[(size_t)wave * BUCK + t];
        uint2 v = ((const uint2*)(ln_out + ((size_t)b * Nn + tok) * Cc))[lane];
        __half2 p0 = *(__half2*)&v.x, p1 = *(__half2*)&v.y;
        float2 f0 = __half22float2(p0), f1 = __half22float2(p1);
        a0 += f0.x; a1 += f0.y; a2 += f1.x; a3 += f1.y;
    }
    const float inv = (cnt > 0) ? (1.0f / (float)cnt) : 0.0f;  // == /max(cnt,1)
    __half2 o0 = __floats2half2_rn(a0 * inv, a1 * inv);
    __half2 o1 = __floats2half2_rn(a2 * inv, a3 * inv);
    uint2 o; o.x = *(unsigned*)&o0; o.y = *(unsigned*)&o1;
    ((uint2*)(grid + (size_t)wave * Cc))[lane] = o;
}

// ---------------- Kernel 3/4: depthwise 3x3, thread = (pixel, 4 channels) ----------------
template <bool FIRST>
__global__ __launch_bounds__(256) void dwconv_kernel(
    const __half* __restrict__ in, const float* __restrict__ wt,
    const float* __restrict__ bias, const float* __restrict__ scale,
    __half* __restrict__ out)
{
    const int idx = blockIdx.x * blockDim.x + threadIdx.x;
    const int c4  = idx & 63;             // 4-channel group
    const int pix = idx >> 6;             // b*HW + hw
    const int hw  = pix & (HWp - 1);
    const int bo  = pix >> 16;
    const int h   = hw >> 8, w = hw & 255;

    float wr[36];
    const float4* wv = (const float4*)(wt + c4 * 36);
    #pragma unroll
    for (int i = 0; i < 9; ++i) {
        float4 qv = wv[i];
        wr[i * 4 + 0] = qv.x; wr[i * 4 + 1] = qv.y;
        wr[i * 4 + 2] = qv.z; wr[i * 4 + 3] = qv.w;
    }

    float acc0 = 0.f, acc1 = 0.f, acc2 = 0.f, acc3 = 0.f;
    #pragma unroll
    for (int ky = 0; ky < 3; ++ky) {
        int ih = h + ky - 1;
        if ((unsigned)ih >= (unsigned)Hh) continue;
        #pragma unroll
        for (int kx = 0; kx < 3; ++kx) {
            int iw = w + kx - 1;
            if ((unsigned)iw >= (unsigned)Ww) continue;
            int ihw = bo * HWp + ih * Ww + iw;
            uint2 r = *(const uint2*)(in + (size_t)ihw * Cc + c4 * 4);
            __half2 p0 = *(__half2*)&r.x, p1 = *(__half2*)&r.y;
            float2 f0 = __half22float2(p0), f1 = __half22float2(p1);
            const int k = ky * 3 + kx;
            acc0 += f0.x * wr[0 * 9 + k];
            acc1 += f0.y * wr[1 * 9 + k];
            acc2 += f1.x * wr[2 * 9 + k];
            acc3 += f1.y * wr[3 * 9 + k];
        }
    }
    float4 bb = *(const float4*)&bias[c4 * 4];
    acc0 += bb.x; acc1 += bb.y; acc2 += bb.z; acc3 += bb.w;
    if (FIRST) {
        acc0 = fmaxf(acc0, 0.f); acc1 = fmaxf(acc1, 0.f);
        acc2 = fmaxf(acc2, 0.f); acc3 = fmaxf(acc3, 0.f);
    } else {
        float4 sv = *(const float4*)&scale[c4 * 4];
        acc0 *= sv.x; acc1 *= sv.y; acc2 *= sv.z; acc3 *= sv.w;
    }
    __half2 o0 = __floats2half2_rn(acc0, acc1);
    __half2 o1 = __floats2half2_rn(acc2, acc3);
    uint2 o; o.x = *(unsigned int*)&o0; o.y = *(unsigned int*)&o1;
    *(uint2*)(out + (size_t)pix * Cc + c4 * 4) = o;
}

// ---------------- Kernel 5: gather + residual ----------------
__global__ __launch_bounds__(256) void gather_add_kernel(
    const float* __restrict__ tokens, const int* __restrict__ iidx,
    const __half* __restrict__ g2, float* __restrict__ out)
{
    __shared__ float gs[Cc][TOK + 1];
    __shared__ int   iid_s[TOK];

    const int tid = threadIdx.x;
    const int bt  = blockIdx.x;
    const int b   = bt / NBLK;
    const int n0  = (bt % NBLK) * TOK;
    const int nvalid = min(TOK, Nn - n0);

    if (tid < nvalid) iid_s[tid] = iidx[b * Nn + n0 + tid];
    __syncthreads();

    const int tq = tid >> 6;
    const int c4 = tid & 63;
    const __half* gbase = g2 + (size_t)b * HWp * Cc;
    for (int t0 = 0; t0 < TOK; t0 += 4) {
        int t = t0 + tq;
        if (t < nvalid) {
            uint2 r = *(const uint2*)(gbase + (size_t)iid_s[t] * Cc + c4 * 4);
            __half2 p0 = *(__half2*)&r.x, p1 = *(__half2*)&r.y;
            float2 f0 = __half22float2(p0), f1 = __half22float2(p1);
            gs[c4 * 4 + 0][t] = f0.x;
            gs[c4 * 4 + 1][t] = f0.y;
            gs[c4 * 4 + 2][t] = f1.x;
            gs[c4 * 4 + 3][t] = f1.y;
        }
    }
    __syncthreads();

    const int tn = tid & 63, q = tid >> 6;
    const float* tb = tokens + (size_t)b * Cc * Nn;
    float* ob = out + (size_t)b * Cc * Nn;
    if (tn < nvalid) {
        #pragma unroll 4
        for (int i = 0; i < 64; ++i) {
            int c = i * 4 + q;
            ob[c * Nn + n0 + tn] = tb[c * Nn + n0 + tn] + gs[c][tn];
        }
    }
}

extern "C" void kernel_launch(void* const* d_in, const int* in_sizes, int n_in,
                              void* d_out, int out_size, void* d_ws, size_t ws_size,
                              hipStream_t stream)
{
    const float* tokens      = (const float*)d_in[0];
    const int*   flatten_idx = (const int*)  d_in[1];
    const int*   inflate_idx = (const int*)  d_in[2];
    const float* lnw         = (const float*)d_in[3];
    const float* lnb         = (const float*)d_in[4];
    const float* w1          = (const float*)d_in[5];
    const float* b1          = (const float*)d_in[6];
    const float* w2          = (const float*)d_in[7];
    const float* b2          = (const float*)d_in[8];
    const float* sw          = (const float*)d_in[9];
    float*       out         = (float*)d_out;

    char* ws = (char*)d_ws;
    const size_t gridBytes  = (size_t)Bb * HWp * Cc * sizeof(__half);   // 33.6 MB x2... (64 MiB total region pair)
    const size_t lnBytes    = (size_t)Bb * Nn * Cc * sizeof(__half);    // 102.4 MB
    __half* grid   = (__half*)ws;
    __half* tmp    = (__half*)(ws + gridBytes);
    __half* ln_out = (__half*)(ws + 2 * gridBytes);
    int*    cntInt = (int*)   (ws + 2 * gridBytes + lnBytes);
    int*    bucket = (int*)   (ws + 2 * gridBytes + lnBytes + (size_t)Bb * HWp * sizeof(int));

    hipMemsetAsync(cntInt, 0, (size_t)Bb * HWp * sizeof(int), stream);

    ln_bucket_kernel<<<Bb * NBLK, 256, 0, stream>>>(tokens, flatten_idx, lnw, lnb,
                                                    ln_out, cntInt, bucket);
    cell_mean_kernel<<<(Bb * HWp) / 4, 256, 0, stream>>>(ln_out, cntInt, bucket, grid);
    dwconv_kernel<true ><<<(Bb * HWp * 64) / 256, 256, 0, stream>>>(grid, w1, b1, nullptr, tmp);
    dwconv_kernel<false><<<(Bb * HWp * 64) / 256, 256, 0, stream>>>(tmp,  w2, b2, sw,      grid);
    gather_add_kernel<<<Bb * NBLK, 256, 0, stream>>>(tokens, inflate_idx, grid, out);
}

// Round 5
// 508.376 us; speedup vs baseline: 1.0534x; 1.0534x over previous
//
#include <hip/hip_runtime.h>
#include <hip/hip_fp16.h>

#define Bb   2
#define Cc   256
#define Nn   100000
#define Hh   256
#define Ww   256
#define HWp  65536
#define TOK  64
#define NBLK ((Nn + TOK - 1) / TOK)     // 1563
#define TOK2 128
#define NB2  ((Nn + TOK2 - 1) / TOK2)   // 782
#define BUCK 24                          // bucket capacity per cell (Poisson-safe)

// ---------------- Kernel 1: LayerNorm(channel) -> ln_out (f16) + bucket fill ----------------
// float4 token loads (16B/lane); lane-local stats for 4 consecutive tokens; no x staging.
// Phase C re-reads tokens (L3-hot) and transposes through an 8.4 KB LDS chunk.
__global__ __launch_bounds__(256) void ln_bucket_kernel(
    const float* __restrict__ tokens, const int* __restrict__ fidx,
    const float* __restrict__ lnw, const float* __restrict__ lnb,
    __half* __restrict__ ln_out, int* __restrict__ cntInt, int* __restrict__ bucket)
{
    __shared__ float  ps [8][TOK2 + 1];
    __shared__ float  pss[8][TOK2 + 1];
    __shared__ float2 ms_s[TOK2];                 // (mu, rsqrt)
    __shared__ __half ch_s[32][TOK2 + 4];         // [cl][t]; row 264B: 8B-aligned, ~2-way banks

    const int tid  = threadIdx.x;
    const int bt   = blockIdx.x;
    const int b    = bt / NB2;
    const int n0   = (bt % NB2) * TOK2;
    const int w    = tid >> 6;
    const int lane = tid & 63;
    const int half = lane >> 5;
    const int lq   = lane & 31;
    const int nvalid = min(TOK2, Nn - n0);        // 128 or 32 -> always %4==0
    const int t0   = lq * 4;                      // this lane's 4 consecutive tokens

    const float* tb = tokens + (size_t)b * Cc * Nn;

    // Phase A: stats, lane-local. (wave w, half h) own channels c = 8k + 2w + h.
    float s0=0,s1=0,s2=0,s3=0, q0=0,q1=0,q2=0,q3=0;
    if (t0 < nvalid) {
        #pragma unroll 8
        for (int k = 0; k < 32; ++k) {
            int c = 8 * k + 2 * w + half;
            float4 v = *(const float4*)&tb[(size_t)c * Nn + n0 + t0];
            s0 += v.x; q0 += v.x * v.x;
            s1 += v.y; q1 += v.y * v.y;
            s2 += v.z; q2 += v.z * v.z;
            s3 += v.w; q3 += v.w * v.w;
        }
    }
    const int w2h = tid >> 5;                     // 0..7
    ps [w2h][t0+0] = s0; ps [w2h][t0+1] = s1; ps [w2h][t0+2] = s2; ps [w2h][t0+3] = s3;
    pss[w2h][t0+0] = q0; pss[w2h][t0+1] = q1; pss[w2h][t0+2] = q2; pss[w2h][t0+3] = q3;

    // Bucket fill: one int atomic per token.
    if (tid < nvalid) {
        int bin  = fidx[b * Nn + n0 + tid];
        int cell = b * HWp + bin;
        int slot = atomicAdd(&cntInt[cell], 1);
        if (slot < BUCK) bucket[(size_t)cell * BUCK + slot] = n0 + tid;
    }
    __syncthreads();

    if (tid < TOK2) {
        float sum = 0.f, ssq = 0.f;
        #pragma unroll
        for (int k = 0; k < 8; ++k) { sum += ps[k][tid]; ssq += pss[k][tid]; }
        float mu  = sum * (1.0f / Cc);
        float var = ssq * (1.0f / Cc) - mu * mu;
        ms_s[tid] = make_float2(mu, rsqrtf(var + 1e-5f));
    }
    __syncthreads();

    const float2 mr0 = ms_s[t0], mr1 = ms_s[t0+1], mr2 = ms_s[t0+2], mr3 = ms_s[t0+3];
    const int tfl = tid >> 5;                     // flush token slot 0..7
    const int clf = tid & 31;                     // flush channel-in-chunk

    // Phase C: 8 chunks of 32 channels: fill (re-read f32, normalize) -> flush (coalesced).
    for (int ch = 0; ch < 8; ++ch) {
        const int cc0 = ch * 32;
        #pragma unroll
        for (int j = 0; j < 4; ++j) {
            int c = cc0 + 8 * j + 2 * w + half;
            float4 v = make_float4(0.f, 0.f, 0.f, 0.f);
            if (t0 < nvalid) v = *(const float4*)&tb[(size_t)c * Nn + n0 + t0];
            float wc = lnw[c], bc = lnb[c];
            float y0 = (v.x - mr0.x) * mr0.y * wc + bc;
            float y1 = (v.y - mr1.x) * mr1.y * wc + bc;
            float y2 = (v.z - mr2.x) * mr2.y * wc + bc;
            float y3 = (v.w - mr3.x) * mr3.y * wc + bc;
            __half2 p0 = __floats2half2_rn(y0, y1);
            __half2 p1 = __floats2half2_rn(y2, y3);
            uint2 pk; pk.x = *(unsigned*)&p0; pk.y = *(unsigned*)&p1;
            *(uint2*)&ch_s[8 * j + 2 * w + half][t0] = pk;   // 4 tokens, one channel
        }
        __syncthreads();
        __half* lobase = ln_out + ((size_t)b * Nn + n0) * Cc + cc0;
        #pragma unroll 4
        for (int it = 0; it < 16; ++it) {
            int t = it * 8 + tfl;
            if (t < nvalid)
                lobase[(size_t)t * Cc + clf] = ch_s[clf][t];  // 64B contiguous per half-wave
        }
        __syncthreads();
    }
}

// ---------------- Kernel 2: per-cell mean (wave per cell), writes ALL cells ----------------
__global__ __launch_bounds__(256) void cell_mean_kernel(
    const __half* __restrict__ ln_out, const int* __restrict__ cntInt,
    const int* __restrict__ bucket, __half* __restrict__ grid)
{
    const int wave = (int)((blockIdx.x * 256 + threadIdx.x) >> 6);  // cell index (b*HW+hw)
    const int lane = threadIdx.x & 63;
    const int b    = wave >> 16;

    int cnt = min(cntInt[wave], BUCK);
    float a0 = 0.f, a1 = 0.f, a2 = 0.f, a3 = 0.f;
    for (int t = 0; t < cnt; ++t) {
        int tok = bucket[(size_t)wave * BUCK + t];
        uint2 v = ((const uint2*)(ln_out + ((size_t)b * Nn + tok) * Cc))[lane];
        __half2 p0 = *(__half2*)&v.x, p1 = *(__half2*)&v.y;
        float2 f0 = __half22float2(p0), f1 = __half22float2(p1);
        a0 += f0.x; a1 += f0.y; a2 += f1.x; a3 += f1.y;
    }
    const float inv = (cnt > 0) ? (1.0f / (float)cnt) : 0.0f;
    __half2 o0 = __floats2half2_rn(a0 * inv, a1 * inv);
    __half2 o1 = __floats2half2_rn(a2 * inv, a3 * inv);
    uint2 o; o.x = *(unsigned*)&o0; o.y = *(unsigned*)&o1;
    ((uint2*)(grid + (size_t)wave * Cc))[lane] = o;
}

// ---------------- Kernel 3/4: depthwise 3x3, thread = (pixel, 4 channels) ----------------
template <bool FIRST>
__global__ __launch_bounds__(256) void dwconv_kernel(
    const __half* __restrict__ in, const float* __restrict__ wt,
    const float* __restrict__ bias, const float* __restrict__ scale,
    __half* __restrict__ out)
{
    const int idx = blockIdx.x * blockDim.x + threadIdx.x;
    const int c4  = idx & 63;
    const int pix = idx >> 6;
    const int hw  = pix & (HWp - 1);
    const int bo  = pix >> 16;
    const int h   = hw >> 8, w = hw & 255;

    float wr[36];
    const float4* wv = (const float4*)(wt + c4 * 36);
    #pragma unroll
    for (int i = 0; i < 9; ++i) {
        float4 qv = wv[i];
        wr[i * 4 + 0] = qv.x; wr[i * 4 + 1] = qv.y;
        wr[i * 4 + 2] = qv.z; wr[i * 4 + 3] = qv.w;
    }

    float acc0 = 0.f, acc1 = 0.f, acc2 = 0.f, acc3 = 0.f;
    #pragma unroll
    for (int ky = 0; ky < 3; ++ky) {
        int ih = h + ky - 1;
        if ((unsigned)ih >= (unsigned)Hh) continue;
        #pragma unroll
        for (int kx = 0; kx < 3; ++kx) {
            int iw = w + kx - 1;
            if ((unsigned)iw >= (unsigned)Ww) continue;
            int ihw = bo * HWp + ih * Ww + iw;
            uint2 r = *(const uint2*)(in + (size_t)ihw * Cc + c4 * 4);
            __half2 p0 = *(__half2*)&r.x, p1 = *(__half2*)&r.y;
            float2 f0 = __half22float2(p0), f1 = __half22float2(p1);
            const int k = ky * 3 + kx;
            acc0 += f0.x * wr[0 * 9 + k];
            acc1 += f0.y * wr[1 * 9 + k];
            acc2 += f1.x * wr[2 * 9 + k];
            acc3 += f1.y * wr[3 * 9 + k];
        }
    }
    float4 bb = *(const float4*)&bias[c4 * 4];
    acc0 += bb.x; acc1 += bb.y; acc2 += bb.z; acc3 += bb.w;
    if (FIRST) {
        acc0 = fmaxf(acc0, 0.f); acc1 = fmaxf(acc1, 0.f);
        acc2 = fmaxf(acc2, 0.f); acc3 = fmaxf(acc3, 0.f);
    } else {
        float4 sv = *(const float4*)&scale[c4 * 4];
        acc0 *= sv.x; acc1 *= sv.y; acc2 *= sv.z; acc3 *= sv.w;
    }
    __half2 o0 = __floats2half2_rn(acc0, acc1);
    __half2 o1 = __floats2half2_rn(acc2, acc3);
    uint2 o; o.x = *(unsigned int*)&o0; o.y = *(unsigned int*)&o1;
    *(uint2*)(out + (size_t)pix * Cc + c4 * 4) = o;
}

// ---------------- Kernel 5: gather + residual (float4 residual path) ----------------
__global__ __launch_bounds__(256) void gather_add_kernel(
    const float* __restrict__ tokens, const int* __restrict__ iidx,
    const __half* __restrict__ g2, float* __restrict__ out)
{
    __shared__ __half gs[TOK][Cc + 4];   // [t][c] halfs; row 520B (8B-aligned)
    __shared__ int    iid_s[TOK];

    const int tid = threadIdx.x;
    const int bt  = blockIdx.x;
    const int b   = bt / NBLK;
    const int n0  = (bt % NBLK) * TOK;
    const int nvalid = min(TOK, Nn - n0);   // 64 or 32 -> %4==0

    if (tid < nvalid) iid_s[tid] = iidx[b * Nn + n0 + tid];
    __syncthreads();

    // Phase A: one token's 512B per wave-instr; uint2 (8B) per lane -> LDS [t][c] (8B write)
    const int tq = tid >> 6, c4 = tid & 63;
    const __half* gbase = g2 + (size_t)b * HWp * Cc;
    for (int tb_ = 0; tb_ < TOK; tb_ += 4) {
        int t = tb_ + tq;
        if (t < nvalid) {
            uint2 r = ((const uint2*)(gbase + (size_t)iid_s[t] * Cc))[c4];
            *(uint2*)&gs[t][c4 * 4] = r;
        }
    }
    __syncthreads();

    // Phase B: float4 residual: lane = (tq4 -> 4 tokens, cg -> channel); 16 iters
    const int tq4 = tid & 15, cg = tid >> 4;
    const int tt0 = tq4 * 4;
    const float* tb = tokens + (size_t)b * Cc * Nn;
    float* ob = out + (size_t)b * Cc * Nn;
    if (tt0 < nvalid) {
        #pragma unroll 4
        for (int it = 0; it < 16; ++it) {
            int c = it * 16 + cg;
            float4 v = *(const float4*)&tb[(size_t)c * Nn + n0 + tt0];
            v.x += __half2float(gs[tt0 + 0][c]);
            v.y += __half2float(gs[tt0 + 1][c]);
            v.z += __half2float(gs[tt0 + 2][c]);
            v.w += __half2float(gs[tt0 + 3][c]);
            *(float4*)&ob[(size_t)c * Nn + n0 + tt0] = v;
        }
    }
}

extern "C" void kernel_launch(void* const* d_in, const int* in_sizes, int n_in,
                              void* d_out, int out_size, void* d_ws, size_t ws_size,
                              hipStream_t stream)
{
    const float* tokens      = (const float*)d_in[0];
    const int*   flatten_idx = (const int*)  d_in[1];
    const int*   inflate_idx = (const int*)  d_in[2];
    const float* lnw         = (const float*)d_in[3];
    const float* lnb         = (const float*)d_in[4];
    const float* w1          = (const float*)d_in[5];
    const float* b1          = (const float*)d_in[6];
    const float* w2          = (const float*)d_in[7];
    const float* b2          = (const float*)d_in[8];
    const float* sw          = (const float*)d_in[9];
    float*       out         = (float*)d_out;

    char* ws = (char*)d_ws;
    const size_t gridBytes = (size_t)Bb * HWp * Cc * sizeof(__half);   // 33.6 MB each
    const size_t lnBytes   = (size_t)Bb * Nn * Cc * sizeof(__half);    // 102.4 MB
    __half* grid   = (__half*)ws;
    __half* tmp    = (__half*)(ws + gridBytes);
    __half* ln_out = (__half*)(ws + 2 * gridBytes);
    int*    cntInt = (int*)   (ws + 2 * gridBytes + lnBytes);
    int*    bucket = (int*)   (ws + 2 * gridBytes + lnBytes + (size_t)Bb * HWp * sizeof(int));

    hipMemsetAsync(cntInt, 0, (size_t)Bb * HWp * sizeof(int), stream);

    ln_bucket_kernel<<<Bb * NB2, 256, 0, stream>>>(tokens, flatten_idx, lnw, lnb,
                                                   ln_out, cntInt, bucket);
    cell_mean_kernel<<<(Bb * HWp) / 4, 256, 0, stream>>>(ln_out, cntInt, bucket, grid);
    dwconv_kernel<true ><<<(Bb * HWp * 64) / 256, 256, 0, stream>>>(grid, w1, b1, nullptr, tmp);
    dwconv_kernel<false><<<(Bb * HWp * 64) / 256, 256, 0, stream>>>(tmp,  w2, b2, sw,      grid);
    gather_add_kernel<<<Bb * NBLK, 256, 0, stream>>>(tokens, inflate_idx, grid, out);
}